// Round 18
// baseline (208.334 us; speedup 1.0000x reference)
//
#include <hip/hip_runtime.h>
#include <cstdint>
#include <cstddef>

// ---------- types ----------
typedef __attribute__((ext_vector_type(8))) short short8;   // 8 bf16 MFMA A/B frag
typedef __attribute__((ext_vector_type(4))) float f32x4;    // 16x16 C/D frag
typedef __attribute__((ext_vector_type(16))) float f32x16;  // 32x32 C/D frag

#define MFMA16(a, b, c) __builtin_amdgcn_mfma_f32_16x16x32_bf16((a), (b), (c), 0, 0, 0)
#define MFMA32(a, b, c) __builtin_amdgcn_mfma_f32_32x32x16_bf16((a), (b), (c), 0, 0, 0)

union F2U { float f; unsigned int u; };
union U4S8 { uint4 u4; unsigned short s[8]; short8 v; };

__device__ __forceinline__ unsigned short f2bf(float f) {
  F2U x; x.f = f;
  unsigned int r = x.u + 0x7fffu + ((x.u >> 16) & 1u);  // RNE
  return (unsigned short)(r >> 16);
}
__device__ __forceinline__ float bf2f(unsigned short s) {
  F2U x; x.u = ((unsigned int)s) << 16;
  return x.f;
}
__device__ __forceinline__ float fexp2(float x) {        // v_exp_f32: D = 2^S0
  float r; asm("v_exp_f32 %0, %1" : "=v"(r) : "v"(x)); return r;
}
__device__ __forceinline__ unsigned int cvtpk(float lo, float hiv) {  // T12
  unsigned int r; asm("v_cvt_pk_bf16_f32 %0, %1, %2" : "=v"(r) : "v"(lo), "v"(hiv)); return r;
}

// ---------- problem constants ----------
#define HIDDEN 2048
#define NHEADS 32
#define NKV 8
#define HDIM 64
#define SEQ 2048
#define BATCH 2
#define NTOK (BATCH * SEQ)   // 4096
#define QKVN 3072            // fused QKV output width (2048 Q | 512 K | 512 V)
#define QSCALE 0.18033688011117309f   // 0.125 * log2(e)

// =====================================================================
// Fused prep kernel (one launch):
//   blocks [0,256):        RoPE cos/sin tables [SEQ][32] fp32
//   blocks [256,4352):     X fp32 -> bf16 (4096 blocks)
//   blocks [4352,6912):    weight transpose+convert (Wq|Wk|Wv|Wo, 2560)
// =====================================================================
__global__ __launch_bounds__(256) void prep_kernel(const float* __restrict__ X,
                                                   const float* __restrict__ Wq,
                                                   const float* __restrict__ Wk,
                                                   const float* __restrict__ Wv,
                                                   const float* __restrict__ Wo,
                                                   unsigned short* __restrict__ Xb,
                                                   unsigned short* __restrict__ Wqkv_t,
                                                   unsigned short* __restrict__ Wot,
                                                   float* __restrict__ ct,
                                                   float* __restrict__ st) {
  __shared__ unsigned short lt[64][72];
  int bid = blockIdx.x;
  const int t = threadIdx.x;

  if (bid < 256) {                       // ---- rope tables ----
    int idx = bid * 256 + t;             // 0 .. 65535
    int s = idx >> 5;
    int i = idx & 31;
    float invf = expf(-(float)i * (9.210340371976184f / 32.0f));  // 10000^(-i/32)
    float f = (float)s * invf;
    ct[idx] = cosf(f);
    st[idx] = sinf(f);
    return;
  }
  bid -= 256;
  if (bid < 4096) {                      // ---- X convert ----
    size_t i = ((size_t)bid * 256 + t) * 8;
    float4 a0 = *(const float4*)(X + i);
    float4 a1 = *(const float4*)(X + i + 4);
    U4S8 p;
    p.s[0] = f2bf(a0.x); p.s[1] = f2bf(a0.y); p.s[2] = f2bf(a0.z); p.s[3] = f2bf(a0.w);
    p.s[4] = f2bf(a1.x); p.s[5] = f2bf(a1.y); p.s[6] = f2bf(a1.z); p.s[7] = f2bf(a1.w);
    *(short8*)(Xb + i) = p.v;
    return;
  }
  bid -= 4096;
  // ---- weight transposes ----
  const float* W; unsigned short* Wt; int N, row_off, bx, by;
  if (bid < 1024)      { W = Wq; Wt = Wqkv_t; N = 2048; row_off = 0;    bx = bid & 31; by = bid >> 5; }
  else if (bid < 1280) { bid -= 1024; W = Wk; Wt = Wqkv_t; N = 512; row_off = 2048; bx = bid & 7; by = bid >> 3; }
  else if (bid < 1536) { bid -= 1280; W = Wv; Wt = Wqkv_t; N = 512; row_off = 2560; bx = bid & 7; by = bid >> 3; }
  else                 { bid -= 1536; W = Wo; Wt = Wot;    N = 2048; row_off = 0;   bx = bid & 31; by = bid >> 5; }
  const int k0 = by * 64, n0 = bx * 64;
  #pragma unroll
  for (int p = 0; p < 4; ++p) {
    int kr = p * 16 + (t >> 4);
    int nc = (t & 15) * 4;
    float4 v = *(const float4*)&W[(size_t)(k0 + kr) * N + n0 + nc];
    lt[nc + 0][kr] = f2bf(v.x);
    lt[nc + 1][kr] = f2bf(v.y);
    lt[nc + 2][kr] = f2bf(v.z);
    lt[nc + 3][kr] = f2bf(v.w);
  }
  __syncthreads();
  #pragma unroll
  for (int p = 0; p < 2; ++p) {
    int nr = p * 32 + (t >> 3);
    int kc = (t & 7) * 8;
    *(short8*)&Wt[(size_t)(row_off + n0 + nr) * HIDDEN + k0 + kc] = *(const short8*)&lt[nr][kc];
  }
}

// =====================================================================
// QKV GEMM, 8-phase schedule with PROPER T4 counted vmcnt:
// 256x256 tile, BK=64, 8 waves (2Mx4N), mfma_32x32x16.
// Pipeline 2 tiles deep: prologue stages tiles 0,1; loop head waits
// vmcnt(8) (tile t landed, t+1 still in flight — NEVER 0 in main loop);
// tile t+2 staged after the last phase barrier (reads of buf done).
// RAW s_barrier throughout (no compiler vmcnt(0) drain).
// =====================================================================
__global__ __launch_bounds__(512, 2) void gemm256_kernel(const unsigned short* __restrict__ Ab,
                                                         const unsigned short* __restrict__ Bt,
                                                         unsigned short* __restrict__ Cp,
                                                         const float* __restrict__ ct,
                                                         const float* __restrict__ st) {
  // A region [0, 65536) bytes, B region [65536, 131072); buf stride 32768.
  __shared__ __align__(16) char smem[131072];

  const int t = threadIdx.x, lane = t & 63, w = t >> 6;   // w 0..7
  const int q32 = lane & 31, hi = lane >> 5;
  const int K = HIDDEN, N = QKVN;

  // T1 XCD swizzle: grid 12 x 16 = 192 blocks (192 % 8 == 0)
  const int orig = blockIdx.y * gridDim.x + blockIdx.x;
  const int nwg  = (int)(gridDim.x * gridDim.y);
  const int cpx  = nwg >> 3;
  const int swz  = (orig & 7) * cpx + (orig >> 3);
  const int m0 = (swz / (int)gridDim.x) * 256;
  const int n0 = (swz % (int)gridDim.x) * 256;

  const int wr = (w >> 2) * 128;        // wave M offset (0/128)
  const int wc = (w & 3) * 64;          // wave N offset (0/64/128/192)

  const int srow0 = w * 8 + (lane >> 3);          // call-0 row (tile-local)
  const int scks  = (lane & 7) ^ (srow0 & 7);
  const unsigned short* PA = Ab + (size_t)(m0 + srow0) * K + scks * 8;
  const unsigned short* PB = Bt + (size_t)(n0 + srow0) * K + scks * 8;

  #define STAGE256(buf, k0)                                                                \
    do {                                                                                   \
      _Pragma("unroll")                                                                    \
      for (int c = 0; c < 4; ++c) {                                                        \
        __builtin_amdgcn_global_load_lds(                                                  \
            (const __attribute__((address_space(1))) unsigned int*)(PA + (size_t)c * 64 * K + (k0)), \
            (__attribute__((address_space(3))) unsigned int*)(smem + (buf) * 32768 + (c * 64 + w * 8) * 128), 16, 0, 0); \
        __builtin_amdgcn_global_load_lds(                                                  \
            (const __attribute__((address_space(1))) unsigned int*)(PB + (size_t)c * 64 * K + (k0)), \
            (__attribute__((address_space(3))) unsigned int*)(smem + 65536 + (buf) * 32768 + (c * 64 + w * 8) * 128), 16, 0, 0); \
      }                                                                                    \
    } while (0)

  f32x16 acc[4][2] = {};   // [i: M 32-rows][j: N 32-cols]
  short8 bfr[2][4];        // B frags, live across phases

  const int NT = K / 64;   // 32

  // ---- prologue: two tiles in flight ----
  STAGE256(0, 0);
  STAGE256(1, 64);

  for (int tt = 0; tt < NT; ++tt) {
    const int buf = tt & 1;
    const char* LA = smem + buf * 32768;
    const char* LB = smem + 65536 + buf * 32768;

    // T4 counted wait: tile tt's 8 loads (oldest) landed; tile tt+1's
    // 8 remain in flight. Only the last iteration drains fully.
    if (tt + 1 < NT) { asm volatile("s_waitcnt vmcnt(8)"); }
    else             { asm volatile("s_waitcnt vmcnt(0)"); }
    __builtin_amdgcn_s_barrier();

    // ---- phase 0: read B frags + A[i=0] ----
    #pragma unroll
    for (int j = 0; j < 2; ++j) {
      int row = wc + j * 32 + q32;
      #pragma unroll
      for (int kq = 0; kq < 4; ++kq)
        bfr[j][kq] = *(const short8*)(LB + row * 128 + (((kq * 2 + hi) ^ (row & 7)) * 16));
    }
    {
      short8 af[4];
      int row = wr + q32;
      #pragma unroll
      for (int kq = 0; kq < 4; ++kq)
        af[kq] = *(const short8*)(LA + row * 128 + (((kq * 2 + hi) ^ (row & 7)) * 16));
      __builtin_amdgcn_s_barrier();
      __builtin_amdgcn_s_setprio(1);
      #pragma unroll
      for (int kq = 0; kq < 4; ++kq) {
        acc[0][0] = MFMA32(af[kq], bfr[0][kq], acc[0][0]);
        acc[0][1] = MFMA32(af[kq], bfr[1][kq], acc[0][1]);
      }
      __builtin_amdgcn_s_setprio(0);
      __builtin_amdgcn_s_barrier();
    }
    // ---- phases 1..3 ----
    #pragma unroll
    for (int i = 1; i < 4; ++i) {
      short8 af[4];
      int row = wr + i * 32 + q32;
      #pragma unroll
      for (int kq = 0; kq < 4; ++kq)
        af[kq] = *(const short8*)(LA + row * 128 + (((kq * 2 + hi) ^ (row & 7)) * 16));
      __builtin_amdgcn_s_barrier();
      __builtin_amdgcn_s_setprio(1);
      #pragma unroll
      for (int kq = 0; kq < 4; ++kq) {
        acc[i][0] = MFMA32(af[kq], bfr[0][kq], acc[i][0]);
        acc[i][1] = MFMA32(af[kq], bfr[1][kq], acc[i][1]);
      }
      __builtin_amdgcn_s_setprio(0);
      __builtin_amdgcn_s_barrier();
    }
    // ---- all waves done reading buf (last phase barrier passed):
    //      stage tile tt+2 into it; latency hides under tile tt+1 ----
    if (tt + 2 < NT) STAGE256(buf, (tt + 2) * 64);
  }

  // ---- epilogue: fused RoPE (Q/K) + bf16 store ----
  const bool isV = (n0 >= 2560);
  const bool isQ = (n0 + 255 < 2048);
  #pragma unroll
  for (int i = 0; i < 4; ++i)
    #pragma unroll
    for (int r = 0; r < 16; ++r) {
      int row = m0 + wr + i * 32 + (r & 3) + 8 * (r >> 2) + 4 * hi;
      int s_tok = row & (SEQ - 1);
      float cc = 0.f, ss = 0.f;
      if (!isV) {
        cc = ct[s_tok * 32 + q32];
        ss = st[s_tok * 32 + q32];
      }
      #pragma unroll
      for (int j = 0; j < 2; ++j) {
        int col = n0 + wc + j * 32 + q32;
        float v = acc[i][j][r];
        float o;
        if (isV) {
          o = v;
        } else {
          float pp = acc[i][j ^ 1][r];          // partner col^32 (const idx)
          o = (j == 0) ? (v * cc - pp * ss) : (v * cc + pp * ss);  // rotate_half
          if (isQ) o *= QSCALE;
        }
        Cp[(size_t)row * N + col] = f2bf(o);
      }
    }
}

// =====================================================================
// GEMM (m97-class, 128x128): used for the output projection (fp32 out).
// =====================================================================
__global__ __launch_bounds__(256) void gemm128_kernel(const unsigned short* __restrict__ Ab,
                                                      const unsigned short* __restrict__ Bt,
                                                      float* __restrict__ Cp,
                                                      int M, int N, int K) {
  __shared__ __align__(16) unsigned short lds_a[128][64];
  __shared__ __align__(16) unsigned short lds_b[128][64];

  const int t = threadIdx.x, lane = t & 63, w = t >> 6;
  const int q32 = lane & 31, hi = lane >> 5;

  const int orig = blockIdx.y * gridDim.x + blockIdx.x;
  const int nwg  = (int)(gridDim.x * gridDim.y);
  const int cpx  = nwg >> 3;                      // nwg % 8 == 0
  const int swz  = (orig & 7) * cpx + (orig >> 3);
  const int m0 = (swz / (int)gridDim.x) * 128;
  const int n0 = (swz % (int)gridDim.x) * 128;

  const int wr = (w >> 1) * 64, wc = (w & 1) * 64;

  f32x16 acc[2][2] = {};   // [m-half][n-half], each 32x32

  for (int k0 = 0; k0 < K; k0 += 64) {
    __syncthreads();
    #pragma unroll
    for (int c = 0; c < 4; ++c) {
      int row = w * 32 + c * 8 + (lane >> 3);
      int cks = (lane & 7) ^ (row & 7);
      __builtin_amdgcn_global_load_lds(
          (const __attribute__((address_space(1))) unsigned int*)(Ab + (size_t)(m0 + row) * K + k0 + cks * 8),
          (__attribute__((address_space(3))) unsigned int*)&lds_a[w * 32 + c * 8][0], 16, 0, 0);
      __builtin_amdgcn_global_load_lds(
          (const __attribute__((address_space(1))) unsigned int*)(Bt + (size_t)(n0 + row) * K + k0 + cks * 8),
          (__attribute__((address_space(3))) unsigned int*)&lds_b[w * 32 + c * 8][0], 16, 0, 0);
    }
    __syncthreads();

    #pragma unroll
    for (int kq = 0; kq < 4; ++kq) {           // K=16 per MFMA32, BK=64
      short8 af[2], bf[2];
      #pragma unroll
      for (int i = 0; i < 2; ++i) {
        int row = wr + i * 32 + q32;
        af[i] = *(const short8*)((const char*)&lds_a[0][0] + row * 128 + (((kq * 2 + hi) ^ (row & 7)) * 16));
      }
      #pragma unroll
      for (int j = 0; j < 2; ++j) {
        int row = wc + j * 32 + q32;
        bf[j] = *(const short8*)((const char*)&lds_b[0][0] + row * 128 + (((kq * 2 + hi) ^ (row & 7)) * 16));
      }
      acc[0][0] = MFMA32(af[0], bf[0], acc[0][0]);
      acc[0][1] = MFMA32(af[0], bf[1], acc[0][1]);
      acc[1][0] = MFMA32(af[1], bf[0], acc[1][0]);
      acc[1][1] = MFMA32(af[1], bf[1], acc[1][1]);
    }
  }

  #pragma unroll
  for (int i = 0; i < 2; ++i)
    #pragma unroll
    for (int j = 0; j < 2; ++j)
      #pragma unroll
      for (int r = 0; r < 16; ++r) {
        int row = m0 + wr + i * 32 + (r & 3) + 8 * (r >> 2) + 4 * hi;
        int col = n0 + wc + j * 32 + q32;
        Cp[(size_t)row * N + col] = acc[i][j][r];
      }
}

// =====================================================================
// V pack/transpose, coalesced (R16, kept).
// =====================================================================
__global__ __launch_bounds__(256) void v_pack_kernel(const unsigned short* __restrict__ QKV,
                                                     unsigned short* __restrict__ Vt) {
  __shared__ unsigned short lt[64][72];   // [d][s], padded
  const int t = threadIdx.x;
  const int s0 = blockIdx.x * 64;
  const int kv = blockIdx.y;
  const int b = blockIdx.z;

  #pragma unroll
  for (int pass = 0; pass < 2; ++pass) {
    int tok = pass * 32 + (t >> 3);
    int d = (t & 7) * 8;
    short8 v = *(const short8*)&QKV[(size_t)(b * SEQ + s0 + tok) * QKVN + 2560 + kv * 64 + d];
    U4S8 u; u.v = v;
    #pragma unroll
    for (int e = 0; e < 8; ++e) lt[d + e][tok] = u.s[e];
  }
  __syncthreads();
  {
    int d = t >> 2;
    int scol = (t & 3) * 16;
    unsigned short* dst = &Vt[(((size_t)(b * NKV + kv)) * HDIM + d) * SEQ + s0 + scol];
    *(uint4*)(dst + 0) = *(const uint4*)&lt[d][scol + 0];
    *(uint4*)(dst + 8) = *(const uint4*)&lt[d][scol + 8];
  }
}

// =====================================================================
// Flash attention, SPLIT-K wave pairs + balanced-pair grid (frozen).
// =====================================================================
#define KVBLK 64

__global__ __launch_bounds__(512, 4) void flash_kernel(const unsigned short* __restrict__ QKV,
                                                       const unsigned short* __restrict__ Vt,
                                                       unsigned short* __restrict__ Ob) {
  const int bx = blockIdx.x;     // 0..7 (pair index)
  const int h = blockIdx.y;
  const int b = blockIdx.z;
  const int kv = h >> 2;
  const int t = threadIdx.x;
  const int lane = t & 63;
  const int w = t >> 6;          // 0..7
  const int p = w >> 1;          // q-row group 0..3
  const int kh = w & 1;          // key half 0/1
  const int q = lane & 31;
  const int hi = lane >> 5;

  __shared__ __align__(16) char smem[34816];
  unsigned short* Klds = (unsigned short*)smem;
  unsigned short* Vlds = (unsigned short*)(smem + 16384);
  float* mlArea = (float*)(smem + 32768);   // [wave][q][{m,l}]

  const unsigned short* Kg = QKV + (size_t)b * SEQ * QKVN + 2048 + kv * 64;
  const unsigned short* Vg = Vt + ((size_t)(b * NKV + kv)) * HDIM * SEQ;
  const unsigned short* Qh = QKV + (size_t)b * SEQ * QKVN + h * 64;

  const int srow = w * 8 + (lane >> 3);
  const int scks = (lane & 7) ^ (srow & 7);
  const unsigned short* Ksrc = Kg + (size_t)srow * QKVN + scks * 8;   // + kt0*QKVN
  const unsigned short* Vsrc = Vg + (size_t)srow * SEQ + scks * 8;    // + kt0

  #define STAGE_KV(buf, kt0)                                                              \
    do {                                                                                  \
      __builtin_amdgcn_global_load_lds(                                                   \
          (const __attribute__((address_space(1))) unsigned int*)(Ksrc + (size_t)(kt0) * QKVN), \
          (__attribute__((address_space(3))) unsigned int*)(Klds + (buf) * 4096 + w * 512), 16, 0, 0); \
      __builtin_amdgcn_global_load_lds(                                                   \
          (const __attribute__((address_space(1))) unsigned int*)(Vsrc + (kt0)),          \
          (__attribute__((address_space(3))) unsigned int*)(Vlds + (buf) * 4096 + w * 512), 16, 0, 0); \
    } while (0)

  #pragma unroll 1
  for (int seg = 0; seg < 2; ++seg) {
    const int qb = seg ? bx : (15 - bx);
    const int wq0 = qb * 128 + p * 32;

    short8 qf[4];
    #pragma unroll
    for (int f = 0; f < 4; ++f)
      qf[f] = *(const short8*)&Qh[(size_t)(wq0 + q) * QKVN + f * 16 + hi * 8];

    f32x16 o0 = {}, o1 = {};
    float m_run = -1e30f, l_run = 0.f;

    const int nt_blk = qb * 2 + 2;

    __syncthreads();
    STAGE_KV(0, 0);
    __syncthreads();
    int cur = 0;

    for (int tt = 0; tt < nt_blk; ++tt) {
      if (tt + 1 < nt_blk) STAGE_KV(cur ^ 1, (tt + 1) * KVBLK);

      const int kbase = tt * KVBLK + kh * 32;
      if (kbase <= wq0 + 31) {
        const unsigned short* Kt = Klds + cur * 4096;
        const unsigned short* Vl = Vlds + cur * 4096;

        f32x16 s = {};
        __builtin_amdgcn_s_setprio(1);
        #pragma unroll
        for (int f = 0; f < 4; ++f) {
          short8 kf = *(const short8*)(Kt + (kh * 32 + q) * 64 + (((f * 2 + hi) ^ (q & 7)) * 8));
          s = MFMA32(kf, qf[f], s);
        }
        __builtin_amdgcn_s_setprio(0);

        if (kbase + 31 > wq0) {
          #pragma unroll
          for (int r = 0; r < 16; ++r) {
            int kl = (r & 3) + 8 * (r >> 2) + 4 * hi;
            if (kbase + kl > wq0 + q) s[r] = -1e30f;
          }
        }

        float mt = -1e30f;
        #pragma unroll
        for (int r = 0; r < 16; ++r) mt = fmaxf(mt, s[r]);
        mt = fmaxf(mt, __shfl_xor(mt, 32, 64));

        const bool resc = __any(mt > m_run + 11.0f);
        if (resc) {
          float mn = fmaxf(m_run, mt);
          float alpha = fexp2(m_run - mn);
          m_run = mn;
          l_run *= alpha;
          #pragma unroll
          for (int r = 0; r < 16; ++r) { o0[r] *= alpha; o1[r] *= alpha; }
        }
        float ls = 0.f;
        #pragma unroll
        for (int r = 0; r < 16; ++r) {
          float pp = fexp2(s[r] - m_run);
          s[r] = pp;
          ls += pp;
        }
        ls += __shfl_xor(ls, 32, 64);
        l_run += ls;

        unsigned int own[8];
        #pragma unroll
        for (int g = 0; g < 8; ++g)
          own[g] = cvtpk(s[2 * g], s[2 * g + 1]);

        __builtin_amdgcn_s_setprio(1);
        {
          unsigned int pa0 = own[0], pb0 = own[2];
          unsigned int pa1 = own[1], pb1 = own[3];
          asm("v_permlane32_swap_b32 %0, %1" : "+v"(pa0), "+v"(pb0));
          asm("v_permlane32_swap_b32 %0, %1" : "+v"(pa1), "+v"(pb1));
          U4S8 pfv;
          pfv.u4.x = pa0;
          pfv.u4.y = pa1;
          pfv.u4.z = pb0;
          pfv.u4.w = pb1;
          int co = ((kh * 4 + hi) ^ (q & 7)) * 8;
          short8 vf0 = *(const short8*)(Vl + q * 64 + co);
          short8 vf1 = *(const short8*)(Vl + (32 + q) * 64 + co);
          o0 = MFMA32(vf0, pfv.v, o0);
          o1 = MFMA32(vf1, pfv.v, o1);
        }
        {
          unsigned int pa0 = own[4], pb0 = own[6];
          unsigned int pa1 = own[5], pb1 = own[7];
          asm("v_permlane32_swap_b32 %0, %1" : "+v"(pa0), "+v"(pb0));
          asm("v_permlane32_swap_b32 %0, %1" : "+v"(pa1), "+v"(pb1));
          U4S8 pfv;
          pfv.u4.x = pa0;
          pfv.u4.y = pa1;
          pfv.u4.z = pb0;
          pfv.u4.w = pb1;
          int co = ((kh * 4 + 2 + hi) ^ (q & 7)) * 8;
          short8 vf0 = *(const short8*)(Vl + q * 64 + co);
          short8 vf1 = *(const short8*)(Vl + (32 + q) * 64 + co);
          o0 = MFMA32(vf0, pfv.v, o0);
          o1 = MFMA32(vf1, pfv.v, o1);
        }
        __builtin_amdgcn_s_setprio(0);
      }

      __syncthreads();
      cur ^= 1;
    }

    // ============ cross-wave (split-K) merge, per pair ============
    if (hi == 0) {
      mlArea[(w * 32 + q) * 2 + 0] = m_run;
      mlArea[(w * 32 + q) * 2 + 1] = l_run;
    }
    __syncthreads();
    const int wo = p * 2 + (kh ^ 1);
    float m_oth = mlArea[(wo * 32 + q) * 2 + 0];
    float l_oth = mlArea[(wo * 32 + q) * 2 + 1];
    float m_tot = fmaxf(m_run, m_oth);
    float alf = fexp2(m_run - m_tot);
    float l_tot = l_run * alf + l_oth * fexp2(m_oth - m_tot);
    #pragma unroll
    for (int r = 0; r < 16; ++r) { o0[r] *= alf; o1[r] *= alf; }

    float* oArea = (float*)smem + (size_t)p * 2048;
    if (kh == 1) {
      float* dst = oArea + lane * 32;
      #pragma unroll
      for (int r = 0; r < 16; ++r) { dst[r] = o0[r]; dst[16 + r] = o1[r]; }
    }
    __syncthreads();
    if (kh == 0) {
      const float* src = oArea + lane * 32;
      #pragma unroll
      for (int r = 0; r < 16; ++r) { o0[r] += src[r]; o1[r] += src[16 + r]; }
    }
    __syncthreads();

    if (kh == 0) {
      unsigned short* lo = (unsigned short*)smem + (size_t)p * 2304;
      float inv = 1.0f / l_tot;
      #pragma unroll
      for (int gg = 0; gg < 8; ++gg) {
        int r = 2 * gg;
        int dl = (r & 3) + 8 * (r >> 2) + 4 * hi;
        unsigned int w0 = (unsigned int)f2bf(o0[r] * inv) | ((unsigned int)f2bf(o0[r + 1] * inv) << 16);
        unsigned int w1 = (unsigned int)f2bf(o1[r] * inv) | ((unsigned int)f2bf(o1[r + 1] * inv) << 16);
        *(unsigned int*)&lo[q * 72 + dl] = w0;
        *(unsigned int*)&lo[q * 72 + 32 + dl] = w1;
      }
      {
        int row = lane >> 1;
        int ch = (lane & 1) * 32;
        uint4 x0 = *(const uint4*)&lo[row * 72 + ch + 0];
        uint4 x1 = *(const uint4*)&lo[row * 72 + ch + 8];
        uint4 x2 = *(const uint4*)&lo[row * 72 + ch + 16];
        uint4 x3 = *(const uint4*)&lo[row * 72 + ch + 24];
        unsigned short* dst = &Ob[(size_t)(b * SEQ + wq0 + row) * (NHEADS * HDIM) + h * HDIM + ch];
        *(uint4*)(dst + 0)  = x0;
        *(uint4*)(dst + 8)  = x1;
        *(uint4*)(dst + 16) = x2;
        *(uint4*)(dst + 24) = x3;
      }
    }
  }
}

// =====================================================================
// launcher
// =====================================================================
extern "C" void kernel_launch(void* const* d_in, const int* in_sizes, int n_in,
                              void* d_out, int out_size, void* d_ws, size_t ws_size,
                              hipStream_t stream) {
  const float* X  = (const float*)d_in[0];
  const float* Wq = (const float*)d_in[1];
  const float* Wk = (const float*)d_in[2];
  const float* Wv = (const float*)d_in[3];
  const float* Wo = (const float*)d_in[4];
  float* out = (float*)d_out;

  char* ws = (char*)d_ws;
  size_t off = 0;
  auto carve = [&](size_t bytes) -> void* {
    void* p = ws + off;
    off += (bytes + 255) & ~(size_t)255;
    return p;
  };
  float* rope_cos = (float*)carve((size_t)SEQ * 32 * 4);
  float* rope_sin = (float*)carve((size_t)SEQ * 32 * 4);
  unsigned short* Xb     = (unsigned short*)carve((size_t)NTOK * HIDDEN * 2);   // reused as Ob
  unsigned short* Wqkv_t = (unsigned short*)carve((size_t)QKVN * HIDDEN * 2);
  unsigned short* Wot    = (unsigned short*)carve((size_t)HIDDEN * HIDDEN * 2);
  unsigned short* QKVb   = (unsigned short*)carve((size_t)NTOK * QKVN * 2);
  unsigned short* Vt     = (unsigned short*)carve((size_t)BATCH * NKV * HDIM * SEQ * 2);
  unsigned short* Ob     = Xb;   // Xb dead after QKV GEMM

  // fused prep: rope tables + X convert + all weight transposes
  prep_kernel<<<dim3(6912), dim3(256), 0, stream>>>(
      X, Wq, Wk, Wv, Wo, Xb, Wqkv_t, Wot, rope_cos, rope_sin);

  // QKV GEMM, 8-phase 256x256 schedule with counted vmcnt, fused RoPE
  gemm256_kernel<<<dim3(QKVN / 256, NTOK / 256), dim3(512), 0, stream>>>(
      Xb, Wqkv_t, QKVb, rope_cos, rope_sin);

  v_pack_kernel<<<dim3(SEQ / 64, NKV, BATCH), dim3(256), 0, stream>>>(QKVb, Vt);

  flash_kernel<<<dim3(8, NHEADS, BATCH), dim3(512), 0, stream>>>(QKVb, Vt, Ob);

  gemm128_kernel<<<dim3(HIDDEN / 128, NTOK / 128), dim3(256), 0, stream>>>(
      Ob, Wot, out, NTOK, HIDDEN, HIDDEN);
}

// Round 19
// 193.851 us; speedup vs baseline: 1.0747x; 1.0747x over previous
//
#include <hip/hip_runtime.h>
#include <cstdint>
#include <cstddef>

// ---------- types ----------
typedef __attribute__((ext_vector_type(8))) short short8;   // 8 bf16 MFMA A/B frag
typedef __attribute__((ext_vector_type(4))) float f32x4;    // 16x16 C/D frag
typedef __attribute__((ext_vector_type(16))) float f32x16;  // 32x32 C/D frag

#define MFMA16(a, b, c) __builtin_amdgcn_mfma_f32_16x16x32_bf16((a), (b), (c), 0, 0, 0)
#define MFMA32(a, b, c) __builtin_amdgcn_mfma_f32_32x32x16_bf16((a), (b), (c), 0, 0, 0)

union F2U { float f; unsigned int u; };
union U4S8 { uint4 u4; unsigned short s[8]; short8 v; };

__device__ __forceinline__ unsigned short f2bf(float f) {
  F2U x; x.f = f;
  unsigned int r = x.u + 0x7fffu + ((x.u >> 16) & 1u);  // RNE
  return (unsigned short)(r >> 16);
}
__device__ __forceinline__ float bf2f(unsigned short s) {
  F2U x; x.u = ((unsigned int)s) << 16;
  return x.f;
}
__device__ __forceinline__ float fexp2(float x) {        // v_exp_f32: D = 2^S0
  float r; asm("v_exp_f32 %0, %1" : "=v"(r) : "v"(x)); return r;
}
__device__ __forceinline__ unsigned int cvtpk(float lo, float hiv) {  // T12
  unsigned int r; asm("v_cvt_pk_bf16_f32 %0, %1, %2" : "=v"(r) : "v"(lo), "v"(hiv)); return r;
}

// ---------- problem constants ----------
#define HIDDEN 2048
#define NHEADS 32
#define NKV 8
#define HDIM 64
#define SEQ 2048
#define BATCH 2
#define NTOK (BATCH * SEQ)   // 4096
#define QKVN 3072            // fused QKV output width (2048 Q | 512 K | 512 V)
#define QSCALE 0.18033688011117309f   // 0.125 * log2(e)

// =====================================================================
// Fused prep kernel (one launch):
//   blocks [0,256):        RoPE cos/sin tables [SEQ][32] fp32
//   blocks [256,4352):     X fp32 -> bf16 (4096 blocks)
//   blocks [4352,6912):    weight transpose+convert (Wq|Wk|Wv|Wo, 2560)
// =====================================================================
__global__ __launch_bounds__(256) void prep_kernel(const float* __restrict__ X,
                                                   const float* __restrict__ Wq,
                                                   const float* __restrict__ Wk,
                                                   const float* __restrict__ Wv,
                                                   const float* __restrict__ Wo,
                                                   unsigned short* __restrict__ Xb,
                                                   unsigned short* __restrict__ Wqkv_t,
                                                   unsigned short* __restrict__ Wot,
                                                   float* __restrict__ ct,
                                                   float* __restrict__ st) {
  __shared__ unsigned short lt[64][72];
  int bid = blockIdx.x;
  const int t = threadIdx.x;

  if (bid < 256) {                       // ---- rope tables ----
    int idx = bid * 256 + t;             // 0 .. 65535
    int s = idx >> 5;
    int i = idx & 31;
    float invf = expf(-(float)i * (9.210340371976184f / 32.0f));  // 10000^(-i/32)
    float f = (float)s * invf;
    ct[idx] = cosf(f);
    st[idx] = sinf(f);
    return;
  }
  bid -= 256;
  if (bid < 4096) {                      // ---- X convert ----
    size_t i = ((size_t)bid * 256 + t) * 8;
    float4 a0 = *(const float4*)(X + i);
    float4 a1 = *(const float4*)(X + i + 4);
    U4S8 p;
    p.s[0] = f2bf(a0.x); p.s[1] = f2bf(a0.y); p.s[2] = f2bf(a0.z); p.s[3] = f2bf(a0.w);
    p.s[4] = f2bf(a1.x); p.s[5] = f2bf(a1.y); p.s[6] = f2bf(a1.z); p.s[7] = f2bf(a1.w);
    *(short8*)(Xb + i) = p.v;
    return;
  }
  bid -= 4096;
  // ---- weight transposes ----
  const float* W; unsigned short* Wt; int N, row_off, bx, by;
  if (bid < 1024)      { W = Wq; Wt = Wqkv_t; N = 2048; row_off = 0;    bx = bid & 31; by = bid >> 5; }
  else if (bid < 1280) { bid -= 1024; W = Wk; Wt = Wqkv_t; N = 512; row_off = 2048; bx = bid & 7; by = bid >> 3; }
  else if (bid < 1536) { bid -= 1280; W = Wv; Wt = Wqkv_t; N = 512; row_off = 2560; bx = bid & 7; by = bid >> 3; }
  else                 { bid -= 1536; W = Wo; Wt = Wot;    N = 2048; row_off = 0;   bx = bid & 31; by = bid >> 5; }
  const int k0 = by * 64, n0 = bx * 64;
  #pragma unroll
  for (int p = 0; p < 4; ++p) {
    int kr = p * 16 + (t >> 4);
    int nc = (t & 15) * 4;
    float4 v = *(const float4*)&W[(size_t)(k0 + kr) * N + n0 + nc];
    lt[nc + 0][kr] = f2bf(v.x);
    lt[nc + 1][kr] = f2bf(v.y);
    lt[nc + 2][kr] = f2bf(v.z);
    lt[nc + 3][kr] = f2bf(v.w);
  }
  __syncthreads();
  #pragma unroll
  for (int p = 0; p < 2; ++p) {
    int nr = p * 32 + (t >> 3);
    int kc = (t & 7) * 8;
    *(short8*)&Wt[(size_t)(row_off + n0 + nr) * HIDDEN + k0 + kc] = *(const short8*)&lt[nr][kc];
  }
}

// =====================================================================
// GEMM: C[M,N] = A[M,K] @ Bt[N,K]^T, all bf16 operands.
// 128x128 tile, BK=64, 4 waves; global_load_lds w16 + XOR chunk swizzle;
// T1 XCD swizzle; mfma_f32_32x32x16_bf16 inner loop.
// MODE 0: fp32 out. MODE 1: bf16 out + FUSED ROPE.
// =====================================================================
template<int MODE>
__global__ __launch_bounds__(256) void gemm128_kernel(const unsigned short* __restrict__ Ab,
                                                      const unsigned short* __restrict__ Bt,
                                                      void* __restrict__ Cp,
                                                      int M, int N, int K,
                                                      const float* __restrict__ ct,
                                                      const float* __restrict__ st) {
  __shared__ __align__(16) unsigned short lds_a[128][64];
  __shared__ __align__(16) unsigned short lds_b[128][64];

  const int t = threadIdx.x, lane = t & 63, w = t >> 6;
  const int q32 = lane & 31, hi = lane >> 5;

  const int orig = blockIdx.y * gridDim.x + blockIdx.x;
  const int nwg  = (int)(gridDim.x * gridDim.y);
  const int cpx  = nwg >> 3;                      // nwg % 8 == 0
  const int swz  = (orig & 7) * cpx + (orig >> 3);
  const int m0 = (swz / (int)gridDim.x) * 128;
  const int n0 = (swz % (int)gridDim.x) * 128;

  const int wr = (w >> 1) * 64, wc = (w & 1) * 64;

  f32x16 acc[2][2] = {};   // [m-half][n-half], each 32x32

  for (int k0 = 0; k0 < K; k0 += 64) {
    __syncthreads();
    #pragma unroll
    for (int c = 0; c < 4; ++c) {
      int row = w * 32 + c * 8 + (lane >> 3);
      int cks = (lane & 7) ^ (row & 7);
      __builtin_amdgcn_global_load_lds(
          (const __attribute__((address_space(1))) unsigned int*)(Ab + (size_t)(m0 + row) * K + k0 + cks * 8),
          (__attribute__((address_space(3))) unsigned int*)&lds_a[w * 32 + c * 8][0], 16, 0, 0);
      __builtin_amdgcn_global_load_lds(
          (const __attribute__((address_space(1))) unsigned int*)(Bt + (size_t)(n0 + row) * K + k0 + cks * 8),
          (__attribute__((address_space(3))) unsigned int*)&lds_b[w * 32 + c * 8][0], 16, 0, 0);
    }
    __syncthreads();

    #pragma unroll
    for (int kq = 0; kq < 4; ++kq) {           // K=16 per MFMA32, BK=64
      short8 af[2], bf[2];
      #pragma unroll
      for (int i = 0; i < 2; ++i) {
        int row = wr + i * 32 + q32;
        af[i] = *(const short8*)((const char*)&lds_a[0][0] + row * 128 + (((kq * 2 + hi) ^ (row & 7)) * 16));
      }
      #pragma unroll
      for (int j = 0; j < 2; ++j) {
        int row = wc + j * 32 + q32;
        bf[j] = *(const short8*)((const char*)&lds_b[0][0] + row * 128 + (((kq * 2 + hi) ^ (row & 7)) * 16));
      }
      acc[0][0] = MFMA32(af[0], bf[0], acc[0][0]);
      acc[0][1] = MFMA32(af[0], bf[1], acc[0][1]);
      acc[1][0] = MFMA32(af[1], bf[0], acc[1][0]);
      acc[1][1] = MFMA32(af[1], bf[1], acc[1][1]);
    }
  }

  if constexpr (MODE == 0) {
    #pragma unroll
    for (int i = 0; i < 2; ++i)
      #pragma unroll
      for (int j = 0; j < 2; ++j)
        #pragma unroll
        for (int r = 0; r < 16; ++r) {
          int row = m0 + wr + i * 32 + (r & 3) + 8 * (r >> 2) + 4 * hi;
          int col = n0 + wc + j * 32 + q32;
          ((float*)Cp)[(size_t)row * N + col] = acc[i][j][r];
        }
  } else {
    const bool isV = (n0 >= 2560);
    const bool isQ = (n0 < 2048);
    #pragma unroll
    for (int i = 0; i < 2; ++i)
      #pragma unroll
      for (int r = 0; r < 16; ++r) {
        int row = m0 + wr + i * 32 + (r & 3) + 8 * (r >> 2) + 4 * hi;
        int s_tok = row & (SEQ - 1);
        float cc = 0.f, ss = 0.f;
        if (!isV) {
          cc = ct[s_tok * 32 + q32];   // fi = lane&31 for BOTH n-halves
          ss = st[s_tok * 32 + q32];
        }
        #pragma unroll
        for (int j = 0; j < 2; ++j) {
          int col = n0 + wc + j * 32 + q32;
          float v = acc[i][j][r];
          float o;
          if (isV) {
            o = v;
          } else {
            float pp = acc[i][j ^ 1][r];        // partner col^32 (const idx)
            o = (j == 0) ? (v * cc - pp * ss) : (v * cc + pp * ss);  // rotate_half
            if (isQ) o *= QSCALE;
          }
          ((unsigned short*)Cp)[(size_t)row * N + col] = f2bf(o);
        }
      }
  }
}

// =====================================================================
// V pack/transpose, coalesced.
// =====================================================================
__global__ __launch_bounds__(256) void v_pack_kernel(const unsigned short* __restrict__ QKV,
                                                     unsigned short* __restrict__ Vt) {
  __shared__ unsigned short lt[64][72];   // [d][s], padded
  const int t = threadIdx.x;
  const int s0 = blockIdx.x * 64;
  const int kv = blockIdx.y;
  const int b = blockIdx.z;

  #pragma unroll
  for (int pass = 0; pass < 2; ++pass) {
    int tok = pass * 32 + (t >> 3);
    int d = (t & 7) * 8;
    short8 v = *(const short8*)&QKV[(size_t)(b * SEQ + s0 + tok) * QKVN + 2560 + kv * 64 + d];
    U4S8 u; u.v = v;
    #pragma unroll
    for (int e = 0; e < 8; ++e) lt[d + e][tok] = u.s[e];
  }
  __syncthreads();
  {
    int d = t >> 2;
    int scol = (t & 3) * 16;
    unsigned short* dst = &Vt[(((size_t)(b * NKV + kv)) * HDIM + d) * SEQ + s0 + scol];
    *(uint4*)(dst + 0) = *(const uint4*)&lt[d][scol + 0];
    *(uint4*)(dst + 8) = *(const uint4*)&lt[d][scol + 8];
  }
}

// =====================================================================
// Flash attention, SPLIT-K wave pairs + balanced-pair grid (frozen).
// =====================================================================
#define KVBLK 64

__global__ __launch_bounds__(512, 4) void flash_kernel(const unsigned short* __restrict__ QKV,
                                                       const unsigned short* __restrict__ Vt,
                                                       unsigned short* __restrict__ Ob) {
  const int bx = blockIdx.x;     // 0..7 (pair index)
  const int h = blockIdx.y;
  const int b = blockIdx.z;
  const int kv = h >> 2;
  const int t = threadIdx.x;
  const int lane = t & 63;
  const int w = t >> 6;          // 0..7
  const int p = w >> 1;          // q-row group 0..3
  const int kh = w & 1;          // key half 0/1
  const int q = lane & 31;
  const int hi = lane >> 5;

  __shared__ __align__(16) char smem[34816];
  unsigned short* Klds = (unsigned short*)smem;
  unsigned short* Vlds = (unsigned short*)(smem + 16384);
  float* mlArea = (float*)(smem + 32768);   // [wave][q][{m,l}]

  const unsigned short* Kg = QKV + (size_t)b * SEQ * QKVN + 2048 + kv * 64;
  const unsigned short* Vg = Vt + ((size_t)(b * NKV + kv)) * HDIM * SEQ;
  const unsigned short* Qh = QKV + (size_t)b * SEQ * QKVN + h * 64;

  const int srow = w * 8 + (lane >> 3);
  const int scks = (lane & 7) ^ (srow & 7);
  const unsigned short* Ksrc = Kg + (size_t)srow * QKVN + scks * 8;   // + kt0*QKVN
  const unsigned short* Vsrc = Vg + (size_t)srow * SEQ + scks * 8;    // + kt0

  #define STAGE_KV(buf, kt0)                                                              \
    do {                                                                                  \
      __builtin_amdgcn_global_load_lds(                                                   \
          (const __attribute__((address_space(1))) unsigned int*)(Ksrc + (size_t)(kt0) * QKVN), \
          (__attribute__((address_space(3))) unsigned int*)(Klds + (buf) * 4096 + w * 512), 16, 0, 0); \
      __builtin_amdgcn_global_load_lds(                                                   \
          (const __attribute__((address_space(1))) unsigned int*)(Vsrc + (kt0)),          \
          (__attribute__((address_space(3))) unsigned int*)(Vlds + (buf) * 4096 + w * 512), 16, 0, 0); \
    } while (0)

  #pragma unroll 1
  for (int seg = 0; seg < 2; ++seg) {
    const int qb = seg ? bx : (15 - bx);
    const int wq0 = qb * 128 + p * 32;

    short8 qf[4];
    #pragma unroll
    for (int f = 0; f < 4; ++f)
      qf[f] = *(const short8*)&Qh[(size_t)(wq0 + q) * QKVN + f * 16 + hi * 8];

    f32x16 o0 = {}, o1 = {};
    float m_run = -1e30f, l_run = 0.f;

    const int nt_blk = qb * 2 + 2;

    __syncthreads();
    STAGE_KV(0, 0);
    __syncthreads();
    int cur = 0;

    for (int tt = 0; tt < nt_blk; ++tt) {
      if (tt + 1 < nt_blk) STAGE_KV(cur ^ 1, (tt + 1) * KVBLK);

      const int kbase = tt * KVBLK + kh * 32;
      if (kbase <= wq0 + 31) {
        const unsigned short* Kt = Klds + cur * 4096;
        const unsigned short* Vl = Vlds + cur * 4096;

        f32x16 s = {};
        __builtin_amdgcn_s_setprio(1);
        #pragma unroll
        for (int f = 0; f < 4; ++f) {
          short8 kf = *(const short8*)(Kt + (kh * 32 + q) * 64 + (((f * 2 + hi) ^ (q & 7)) * 8));
          s = MFMA32(kf, qf[f], s);
        }
        __builtin_amdgcn_s_setprio(0);

        if (kbase + 31 > wq0) {
          #pragma unroll
          for (int r = 0; r < 16; ++r) {
            int kl = (r & 3) + 8 * (r >> 2) + 4 * hi;
            if (kbase + kl > wq0 + q) s[r] = -1e30f;
          }
        }

        float mt = -1e30f;
        #pragma unroll
        for (int r = 0; r < 16; ++r) mt = fmaxf(mt, s[r]);
        mt = fmaxf(mt, __shfl_xor(mt, 32, 64));

        const bool resc = __any(mt > m_run + 11.0f);
        if (resc) {
          float mn = fmaxf(m_run, mt);
          float alpha = fexp2(m_run - mn);
          m_run = mn;
          l_run *= alpha;
          #pragma unroll
          for (int r = 0; r < 16; ++r) { o0[r] *= alpha; o1[r] *= alpha; }
        }
        float ls = 0.f;
        #pragma unroll
        for (int r = 0; r < 16; ++r) {
          float pp = fexp2(s[r] - m_run);
          s[r] = pp;
          ls += pp;
        }
        ls += __shfl_xor(ls, 32, 64);
        l_run += ls;

        unsigned int own[8];
        #pragma unroll
        for (int g = 0; g < 8; ++g)
          own[g] = cvtpk(s[2 * g], s[2 * g + 1]);

        __builtin_amdgcn_s_setprio(1);
        {
          unsigned int pa0 = own[0], pb0 = own[2];
          unsigned int pa1 = own[1], pb1 = own[3];
          asm("v_permlane32_swap_b32 %0, %1" : "+v"(pa0), "+v"(pb0));
          asm("v_permlane32_swap_b32 %0, %1" : "+v"(pa1), "+v"(pb1));
          U4S8 pfv;
          pfv.u4.x = pa0;
          pfv.u4.y = pa1;
          pfv.u4.z = pb0;
          pfv.u4.w = pb1;
          int co = ((kh * 4 + hi) ^ (q & 7)) * 8;
          short8 vf0 = *(const short8*)(Vl + q * 64 + co);
          short8 vf1 = *(const short8*)(Vl + (32 + q) * 64 + co);
          o0 = MFMA32(vf0, pfv.v, o0);
          o1 = MFMA32(vf1, pfv.v, o1);
        }
        {
          unsigned int pa0 = own[4], pb0 = own[6];
          unsigned int pa1 = own[5], pb1 = own[7];
          asm("v_permlane32_swap_b32 %0, %1" : "+v"(pa0), "+v"(pb0));
          asm("v_permlane32_swap_b32 %0, %1" : "+v"(pa1), "+v"(pb1));
          U4S8 pfv;
          pfv.u4.x = pa0;
          pfv.u4.y = pa1;
          pfv.u4.z = pb0;
          pfv.u4.w = pb1;
          int co = ((kh * 4 + 2 + hi) ^ (q & 7)) * 8;
          short8 vf0 = *(const short8*)(Vl + q * 64 + co);
          short8 vf1 = *(const short8*)(Vl + (32 + q) * 64 + co);
          o0 = MFMA32(vf0, pfv.v, o0);
          o1 = MFMA32(vf1, pfv.v, o1);
        }
        __builtin_amdgcn_s_setprio(0);
      }

      __syncthreads();
      cur ^= 1;
    }

    // ============ cross-wave (split-K) merge, per pair ============
    if (hi == 0) {
      mlArea[(w * 32 + q) * 2 + 0] = m_run;
      mlArea[(w * 32 + q) * 2 + 1] = l_run;
    }
    __syncthreads();
    const int wo = p * 2 + (kh ^ 1);
    float m_oth = mlArea[(wo * 32 + q) * 2 + 0];
    float l_oth = mlArea[(wo * 32 + q) * 2 + 1];
    float m_tot = fmaxf(m_run, m_oth);
    float alf = fexp2(m_run - m_tot);
    float l_tot = l_run * alf + l_oth * fexp2(m_oth - m_tot);
    #pragma unroll
    for (int r = 0; r < 16; ++r) { o0[r] *= alf; o1[r] *= alf; }

    float* oArea = (float*)smem + (size_t)p * 2048;
    if (kh == 1) {
      float* dst = oArea + lane * 32;
      #pragma unroll
      for (int r = 0; r < 16; ++r) { dst[r] = o0[r]; dst[16 + r] = o1[r]; }
    }
    __syncthreads();
    if (kh == 0) {
      const float* src = oArea + lane * 32;
      #pragma unroll
      for (int r = 0; r < 16; ++r) { o0[r] += src[r]; o1[r] += src[16 + r]; }
    }
    __syncthreads();

    if (kh == 0) {
      unsigned short* lo = (unsigned short*)smem + (size_t)p * 2304;
      float inv = 1.0f / l_tot;
      #pragma unroll
      for (int gg = 0; gg < 8; ++gg) {
        int r = 2 * gg;
        int dl = (r & 3) + 8 * (r >> 2) + 4 * hi;
        unsigned int w0 = (unsigned int)f2bf(o0[r] * inv) | ((unsigned int)f2bf(o0[r + 1] * inv) << 16);
        unsigned int w1 = (unsigned int)f2bf(o1[r] * inv) | ((unsigned int)f2bf(o1[r + 1] * inv) << 16);
        *(unsigned int*)&lo[q * 72 + dl] = w0;
        *(unsigned int*)&lo[q * 72 + 32 + dl] = w1;
      }
      {
        int row = lane >> 1;
        int ch = (lane & 1) * 32;
        uint4 x0 = *(const uint4*)&lo[row * 72 + ch + 0];
        uint4 x1 = *(const uint4*)&lo[row * 72 + ch + 8];
        uint4 x2 = *(const uint4*)&lo[row * 72 + ch + 16];
        uint4 x3 = *(const uint4*)&lo[row * 72 + ch + 24];
        unsigned short* dst = &Ob[(size_t)(b * SEQ + wq0 + row) * (NHEADS * HDIM) + h * HDIM + ch];
        *(uint4*)(dst + 0)  = x0;
        *(uint4*)(dst + 8)  = x1;
        *(uint4*)(dst + 16) = x2;
        *(uint4*)(dst + 24) = x3;
      }
    }
  }
}

// =====================================================================
// launcher
// =====================================================================
extern "C" void kernel_launch(void* const* d_in, const int* in_sizes, int n_in,
                              void* d_out, int out_size, void* d_ws, size_t ws_size,
                              hipStream_t stream) {
  const float* X  = (const float*)d_in[0];
  const float* Wq = (const float*)d_in[1];
  const float* Wk = (const float*)d_in[2];
  const float* Wv = (const float*)d_in[3];
  const float* Wo = (const float*)d_in[4];
  float* out = (float*)d_out;

  char* ws = (char*)d_ws;
  size_t off = 0;
  auto carve = [&](size_t bytes) -> void* {
    void* p = ws + off;
    off += (bytes + 255) & ~(size_t)255;
    return p;
  };
  float* rope_cos = (float*)carve((size_t)SEQ * 32 * 4);
  float* rope_sin = (float*)carve((size_t)SEQ * 32 * 4);
  unsigned short* Xb     = (unsigned short*)carve((size_t)NTOK * HIDDEN * 2);   // reused as Ob
  unsigned short* Wqkv_t = (unsigned short*)carve((size_t)QKVN * HIDDEN * 2);
  unsigned short* Wot    = (unsigned short*)carve((size_t)HIDDEN * HIDDEN * 2);
  unsigned short* QKVb   = (unsigned short*)carve((size_t)NTOK * QKVN * 2);
  unsigned short* Vt     = (unsigned short*)carve((size_t)BATCH * NKV * HDIM * SEQ * 2);
  unsigned short* Ob     = Xb;   // Xb dead after QKV GEMM

  // fused prep: rope tables + X convert + all weight transposes
  prep_kernel<<<dim3(6912), dim3(256), 0, stream>>>(
      X, Wq, Wk, Wv, Wo, Xb, Wqkv_t, Wot, rope_cos, rope_sin);

  // QKV GEMM with fused RoPE (+ Q pre-scale) in the epilogue
  gemm128_kernel<1><<<dim3(QKVN / 128, NTOK / 128), dim3(256), 0, stream>>>(
      Xb, Wqkv_t, QKVb, NTOK, QKVN, HIDDEN, rope_cos, rope_sin);

  v_pack_kernel<<<dim3(SEQ / 64, NKV, BATCH), dim3(256), 0, stream>>>(QKVb, Vt);

  flash_kernel<<<dim3(8, NHEADS, BATCH), dim3(512), 0, stream>>>(QKVb, Vt, Ob);

  gemm128_kernel<0><<<dim3(HIDDEN / 128, NTOK / 128), dim3(256), 0, stream>>>(
      Ob, Wot, out, NTOK, HIDDEN, HIDDEN, nullptr, nullptr);
}